// Round 17
// baseline (72.613 us; speedup 1.0000x reference)
//
#include <hip/hip_runtime.h>

// HeteroConv copy_u + segment_sum.
// Ladder: 858 -> 71.5us (R16). Structure: fixed-stride bins (bin=dst>>8),
// fused {bin-scatter + bf16 convert} -> per-bin LDS counting sort (in-place)
// -> parallel bf16 accum -> exact spill. Facts: per-edge global return
// atomics = 43us/M flat (eliminated); accum is at its gather-traffic floor
// (~26us: 1M x 128B bf16 rows + 25.6MB out ~ 6TB/s effective).
// R17 (this): orchestration shave -- (1) init kernel -> relative cursors +
// one tiny memset, (2) bin_sort at 512 threads (halved loop trips),
// (3) scatter at 16 edges/thread (EPB 8192: halves blocks + reservation
// atomics). Accum untouched.

#define DPB 256          // dsts per bin
#define BIN_SHIFT 8
#define EPB 8192         // edges per scatter block (512 thr x 16)

__device__ __forceinline__ unsigned short f2bf(float f) {
    unsigned u = __float_as_uint(f);
    unsigned r = u + 0x7FFFu + ((u >> 16) & 1u);   // round-to-nearest-even
    return (unsigned short)(r >> 16);
}
__device__ __forceinline__ unsigned pack2(float lo, float hi) {
    return (unsigned)f2bf(lo) | ((unsigned)f2bf(hi) << 16);
}

// ---- tier-0 phase 1: fused bin-scatter + bf16 convert ----
// Relative cursors (start at 0): reservation base = atomicAdd(&cursor[k],c);
// global slot = k*cap + base + r. Overflow (base+r >= cap) -> spill list.
// The grid-strided bf16 convert runs between the reservation atomics and
// their use, hiding their latency.
__global__ void scatter_convert_kernel(const float4* __restrict__ src4,
                                       uint4* __restrict__ srcb, long n8,
                                       const int* __restrict__ esrc,
                                       const int* __restrict__ edst,
                                       int* __restrict__ cursor,
                                       int* __restrict__ packed, int cap,
                                       int2* __restrict__ spill,
                                       int* __restrict__ spill_cnt,
                                       int spill_max, int nbins, int n) {
    __shared__ int lc[1024];
    __shared__ int lbase[1024];
    __shared__ int lrank[1024];
    int t = threadIdx.x;
    for (int k = t; k < nbins; k += blockDim.x) { lc[k] = 0; lrank[k] = 0; }
    __syncthreads();

    int i0 = blockIdx.x * EPB + t * 16;
    bool fast = (i0 + 15 < n);

    if (fast) {
#pragma unroll
        for (int c4 = 0; c4 < 4; ++c4) {
            int4 d = *reinterpret_cast<const int4*>(edst + i0 + c4 * 4);
            atomicAdd(&lc[d.x >> BIN_SHIFT], 1);
            atomicAdd(&lc[d.y >> BIN_SHIFT], 1);
            atomicAdd(&lc[d.z >> BIN_SHIFT], 1);
            atomicAdd(&lc[d.w >> BIN_SHIFT], 1);
        }
    } else {
        for (int k = 0; k < 16; ++k) {
            int i = i0 + k;
            if (i < n) atomicAdd(&lc[edst[i] >> BIN_SHIFT], 1);
        }
    }
    __syncthreads();

    // reserve ranges (return atomics; ~nbins per block, halved block count)
    for (int k = t; k < nbins; k += blockDim.x) {
        int c = lc[k];
        if (c > 0) lbase[k] = atomicAdd(&cursor[k], c);
    }

    // fused bf16 convert: independent streaming work hides atomic latency
    long nthreads = (long)gridDim.x * blockDim.x;
    for (long u = (long)blockIdx.x * blockDim.x + t; u < n8; u += nthreads) {
        float4 a = src4[u * 2];
        float4 b = src4[u * 2 + 1];
        uint4 o;
        o.x = pack2(a.x, a.y);
        o.y = pack2(a.z, a.w);
        o.z = pack2(b.x, b.y);
        o.w = pack2(b.z, b.w);
        srcb[u] = o;
    }
    __syncthreads();

    if (fast) {
#pragma unroll
        for (int c4 = 0; c4 < 4; ++c4) {
            int4 d4 = *reinterpret_cast<const int4*>(edst + i0 + c4 * 4);
            int4 s4 = *reinterpret_cast<const int4*>(esrc + i0 + c4 * 4);
            int dd[4] = {d4.x, d4.y, d4.z, d4.w};
            int ss[4] = {s4.x, s4.y, s4.z, s4.w};
#pragma unroll
            for (int e = 0; e < 4; ++e) {
                int d = dd[e], s = ss[e];
                int k = d >> BIN_SHIFT;
                int r = lbase[k] + atomicAdd(&lrank[k], 1);
                if (r < cap) {
                    packed[(size_t)k * cap + r] = ((d & (DPB - 1)) << 20) | s;
                } else {
                    int sp = atomicAdd(spill_cnt, 1);
                    if (sp < spill_max) spill[sp] = make_int2(s, d);
                }
            }
        }
    } else {
        for (int kk = 0; kk < 16; ++kk) {
            int i = i0 + kk;
            if (i < n) {
                int d = edst[i], s = esrc[i];
                int k = d >> BIN_SHIFT;
                int r = lbase[k] + atomicAdd(&lrank[k], 1);
                if (r < cap) {
                    packed[(size_t)k * cap + r] = ((d & (DPB - 1)) << 20) | s;
                } else {
                    int sp = atomicAdd(spill_cnt, 1);
                    if (sp < spill_max) spill[sp] = make_int2(s, d);
                }
            }
        }
    }
}

// ---- tier-0 phase 2: per-bin LDS counting sort, in-place, 512 threads ----
// dynamic LDS: buf[cap] + cnt[256] + base[256]. All barriers uniform.
__global__ void bin_sort_lds_kernel(int* __restrict__ packed,
                                    const int* __restrict__ cursor,
                                    int* __restrict__ offsets,
                                    int* __restrict__ ends,
                                    int cap, int nbins, int n_dst) {
    extern __shared__ int smem[];
    int* buf  = smem;          // [cap]
    int* cnt  = smem + cap;    // [256]
    int* base = cnt + DPB;     // [256]
    int t = threadIdx.x;       // 512 threads
    int b = blockIdx.x;
    int start = b * cap;
    int count = cursor[b];     // relative fill level
    if (count > cap) count = cap;
    if (count < 0) count = 0;

    for (int j = t; j < count; j += 512) buf[j] = packed[start + j];
    if (t < DPB) cnt[t] = 0;
    __syncthreads();

    for (int j = t; j < count; j += 512)
        atomicAdd(&cnt[(buf[j] >> 20) & (DPB - 1)], 1);
    __syncthreads();

    int v = 0;
    if (t < DPB) { v = cnt[t]; base[t] = v; }
    __syncthreads();
    for (int o = 1; o < DPB; o <<= 1) {
        int u = (t >= o && t < DPB) ? base[t - o] : 0;
        __syncthreads();
        if (t < DPB) base[t] += u;
        __syncthreads();
    }
    if (t < DPB) {
        int excl = base[t] - v;
        base[t] = excl;
        cnt[t] = 0;
        int g = (b << BIN_SHIFT) + t;
        if (g < n_dst) {
            offsets[g] = start + excl;
            ends[g]    = start + excl + v;
        }
    }
    __syncthreads();

    for (int j = t; j < count; j += 512) {
        int p = buf[j];
        int dl = (p >> 20) & (DPB - 1);
        int r = atomicAdd(&cnt[dl], 1);
        packed[start + base[dl] + r] = p & 0xFFFFF;   // src index only
    }
}

// ---- tier-0 phase 3: parallel bf16 accum (proven; traffic-floor) ----
__global__ void accum_fix_bf16(const uint4* __restrict__ srcb,
                               const int* __restrict__ offsets,
                               const int* __restrict__ ends,
                               const int* __restrict__ sorted_src,
                               float4* __restrict__ out4, int n_dst) {
    int node = blockIdx.x * (blockDim.x >> 6) + (threadIdx.x >> 6);
    if (node >= n_dst) return;
    int lane = threadIdx.x & 63;
    int g = lane >> 3;
    int q = lane & 7;

    int start = offsets[node];
    int end = ends[node];

    float a0 = 0.f, a1 = 0.f, a2 = 0.f, a3 = 0.f;
    float a4 = 0.f, a5 = 0.f, a6 = 0.f, a7 = 0.f;

    for (int j = start + g; j < end; j += 8) {
        int s = sorted_src[j];
        uint4 v = srcb[(size_t)s * 8 + q];
        a0 += __uint_as_float(v.x << 16);
        a1 += __uint_as_float(v.x & 0xFFFF0000u);
        a2 += __uint_as_float(v.y << 16);
        a3 += __uint_as_float(v.y & 0xFFFF0000u);
        a4 += __uint_as_float(v.z << 16);
        a5 += __uint_as_float(v.z & 0xFFFF0000u);
        a6 += __uint_as_float(v.w << 16);
        a7 += __uint_as_float(v.w & 0xFFFF0000u);
    }

#pragma unroll
    for (int off = 8; off < 64; off <<= 1) {    // uniform across the wave
        a0 += __shfl_xor(a0, off);
        a1 += __shfl_xor(a1, off);
        a2 += __shfl_xor(a2, off);
        a3 += __shfl_xor(a3, off);
        a4 += __shfl_xor(a4, off);
        a5 += __shfl_xor(a5, off);
        a6 += __shfl_xor(a6, off);
        a7 += __shfl_xor(a7, off);
    }
    if (g == 0) {
        size_t o = (size_t)node * 16 + q * 2;
        out4[o]     = make_float4(a0, a1, a2, a3);
        out4[o + 1] = make_float4(a4, a5, a6, a7);
    }
}

// ---- tier-0 phase 4: apply spill edges exactly (runs AFTER accum) ----
__global__ void spill_add_kernel(const float* __restrict__ src_emb,
                                 const int2* __restrict__ spill,
                                 const int* __restrict__ spill_cnt,
                                 int spill_max, float* __restrict__ out) {
    int n = *spill_cnt;
    if (n > spill_max) n = spill_max;
    long total = (long)n * 16;
    long stride = (long)gridDim.x * blockDim.x;
    for (long u = (long)blockIdx.x * blockDim.x + threadIdx.x; u < total;
         u += stride) {
        int e = (int)(u >> 4);
        int q = (int)(u & 15);
        int2 p = spill[e];
        const float* row = src_emb + (size_t)p.x * 64 + q * 4;
        float* orow = out + (size_t)p.y * 64 + q * 4;
        atomicAdd(orow + 0, row[0]);
        atomicAdd(orow + 1, row[1]);
        atomicAdd(orow + 2, row[2]);
        atomicAdd(orow + 3, row[3]);
    }
}

// ============ tier-1: proven R15 pipeline (81.4us) ============

__global__ void convert_bf16_kernel(const float4* __restrict__ src4,
                                    uint4* __restrict__ srcb, long n8) {
    long t = (long)blockIdx.x * blockDim.x + threadIdx.x;
    if (t >= n8) return;
    float4 a = src4[t * 2];
    float4 b = src4[t * 2 + 1];
    uint4 o;
    o.x = pack2(a.x, a.y);
    o.y = pack2(a.z, a.w);
    o.z = pack2(b.x, b.y);
    o.w = pack2(b.z, b.w);
    srcb[t] = o;
}

__global__ void bin_hist_kernel(const int* __restrict__ edst,
                                int* __restrict__ binCounts,
                                int nbins, int n) {
    __shared__ int lc[1024];
    int t = threadIdx.x;
    for (int k = t; k < nbins; k += blockDim.x) lc[k] = 0;
    __syncthreads();
    int i0 = blockIdx.x * 4096 + t * 8;
    if (i0 + 7 < n) {
        int4 d0 = *reinterpret_cast<const int4*>(edst + i0);
        int4 d1 = *reinterpret_cast<const int4*>(edst + i0 + 4);
        atomicAdd(&lc[d0.x >> BIN_SHIFT], 1);
        atomicAdd(&lc[d0.y >> BIN_SHIFT], 1);
        atomicAdd(&lc[d0.z >> BIN_SHIFT], 1);
        atomicAdd(&lc[d0.w >> BIN_SHIFT], 1);
        atomicAdd(&lc[d1.x >> BIN_SHIFT], 1);
        atomicAdd(&lc[d1.y >> BIN_SHIFT], 1);
        atomicAdd(&lc[d1.z >> BIN_SHIFT], 1);
        atomicAdd(&lc[d1.w >> BIN_SHIFT], 1);
    } else {
        for (int k = 0; k < 8; ++k) {
            int i = i0 + k;
            if (i < n) atomicAdd(&lc[edst[i] >> BIN_SHIFT], 1);
        }
    }
    __syncthreads();
    for (int k = t; k < nbins; k += blockDim.x) {
        int c = lc[k];
        if (c > 0) atomicAdd(&binCounts[k], c);
    }
}

__global__ void bin_scan_kernel(int* __restrict__ binOff,
                                int* __restrict__ cursor, int nbins) {
    __shared__ int lds[1024];
    int t = threadIdx.x;
    int v = (t < nbins) ? binOff[t] : 0;
    lds[t] = v;
    __syncthreads();
    for (int off = 1; off < 1024; off <<= 1) {
        int u = (t >= off) ? lds[t - off] : 0;
        __syncthreads();
        lds[t] += u;
        __syncthreads();
    }
    if (t < nbins) {
        int base = lds[t] - v;
        binOff[t] = base;
        cursor[t] = base;
    }
    if (t == 1023) binOff[nbins] = lds[t];
}

__global__ void bin_scatter_kernel(const int* __restrict__ esrc,
                                   const int* __restrict__ edst,
                                   int* __restrict__ cursor,
                                   int* __restrict__ packed,
                                   int nbins, int n) {
    __shared__ int lc[1024];
    __shared__ int lbase[1024];
    __shared__ int lrank[1024];
    int t = threadIdx.x;
    for (int k = t; k < nbins; k += blockDim.x) { lc[k] = 0; lrank[k] = 0; }
    __syncthreads();
    int i0 = blockIdx.x * 4096 + t * 8;
    bool fast = (i0 + 7 < n);
    if (fast) {
        int4 d0 = *reinterpret_cast<const int4*>(edst + i0);
        int4 d1 = *reinterpret_cast<const int4*>(edst + i0 + 4);
        atomicAdd(&lc[d0.x >> BIN_SHIFT], 1);
        atomicAdd(&lc[d0.y >> BIN_SHIFT], 1);
        atomicAdd(&lc[d0.z >> BIN_SHIFT], 1);
        atomicAdd(&lc[d0.w >> BIN_SHIFT], 1);
        atomicAdd(&lc[d1.x >> BIN_SHIFT], 1);
        atomicAdd(&lc[d1.y >> BIN_SHIFT], 1);
        atomicAdd(&lc[d1.z >> BIN_SHIFT], 1);
        atomicAdd(&lc[d1.w >> BIN_SHIFT], 1);
    } else {
        for (int k = 0; k < 8; ++k) {
            int i = i0 + k;
            if (i < n) atomicAdd(&lc[edst[i] >> BIN_SHIFT], 1);
        }
    }
    __syncthreads();
    for (int k = t; k < nbins; k += blockDim.x) {
        int c = lc[k];
        if (c > 0) lbase[k] = atomicAdd(&cursor[k], c);
    }
    __syncthreads();
    if (fast) {
        int4 s0 = *reinterpret_cast<const int4*>(esrc + i0);
        int4 s1 = *reinterpret_cast<const int4*>(esrc + i0 + 4);
        int4 d0 = *reinterpret_cast<const int4*>(edst + i0);
        int4 d1 = *reinterpret_cast<const int4*>(edst + i0 + 4);
        int dd[8] = {d0.x, d0.y, d0.z, d0.w, d1.x, d1.y, d1.z, d1.w};
        int ss[8] = {s0.x, s0.y, s0.z, s0.w, s1.x, s1.y, s1.z, s1.w};
#pragma unroll
        for (int e = 0; e < 8; ++e) {
            int k = dd[e] >> BIN_SHIFT;
            int r = atomicAdd(&lrank[k], 1);
            packed[lbase[k] + r] = ((dd[e] & (DPB - 1)) << 20) | ss[e];
        }
    } else {
        for (int kk = 0; kk < 8; ++kk) {
            int i = i0 + kk;
            if (i < n) {
                int d = edst[i];
                int k = d >> BIN_SHIFT;
                int r = atomicAdd(&lrank[k], 1);
                packed[lbase[k] + r] = ((d & (DPB - 1)) << 20) | esrc[i];
            }
        }
    }
}

__global__ void bin_sort_kernel(const int* __restrict__ packed,
                                const int* __restrict__ binOff,
                                int* __restrict__ sorted_src,
                                int* __restrict__ offsets,
                                int nbins, int n_dst, int n_edges) {
    __shared__ int cnt[DPB];
    __shared__ int base[DPB];
    int t = threadIdx.x;
    int b = blockIdx.x;
    int start = binOff[b];
    int end = binOff[b + 1];
    cnt[t] = 0;
    __syncthreads();
    for (int j = start + t; j < end; j += DPB)
        atomicAdd(&cnt[(packed[j] >> 20) & (DPB - 1)], 1);
    __syncthreads();
    int v = cnt[t];
    base[t] = v;
    __syncthreads();
    for (int o = 1; o < DPB; o <<= 1) {
        int u = (t >= o) ? base[t - o] : 0;
        __syncthreads();
        base[t] += u;
        __syncthreads();
    }
    int my_excl = base[t] - v;
    __syncthreads();
    base[t] = my_excl;
    cnt[t] = 0;
    int g = (b << BIN_SHIFT) + t;
    if (g < n_dst) offsets[g] = start + my_excl;
    if (b == nbins - 1 && t == 0) offsets[n_dst] = n_edges;
    __syncthreads();
    for (int j = start + t; j < end; j += DPB) {
        int p = packed[j];
        int dl = (p >> 20) & (DPB - 1);
        int r = atomicAdd(&cnt[dl], 1);
        sorted_src[start + base[dl] + r] = p & 0xFFFFF;
    }
}

__global__ void accum_abs_bf16(const uint4* __restrict__ srcb,
                               const int* __restrict__ offsets,
                               const int* __restrict__ sorted_src,
                               float4* __restrict__ out4, int n_dst) {
    int node = blockIdx.x * (blockDim.x >> 6) + (threadIdx.x >> 6);
    if (node >= n_dst) return;
    int lane = threadIdx.x & 63;
    int g = lane >> 3;
    int q = lane & 7;
    int start = offsets[node];
    int end = offsets[node + 1];
    float a0 = 0.f, a1 = 0.f, a2 = 0.f, a3 = 0.f;
    float a4 = 0.f, a5 = 0.f, a6 = 0.f, a7 = 0.f;
    for (int j = start + g; j < end; j += 8) {
        int s = sorted_src[j];
        uint4 v = srcb[(size_t)s * 8 + q];
        a0 += __uint_as_float(v.x << 16);
        a1 += __uint_as_float(v.x & 0xFFFF0000u);
        a2 += __uint_as_float(v.y << 16);
        a3 += __uint_as_float(v.y & 0xFFFF0000u);
        a4 += __uint_as_float(v.z << 16);
        a5 += __uint_as_float(v.z & 0xFFFF0000u);
        a6 += __uint_as_float(v.w << 16);
        a7 += __uint_as_float(v.w & 0xFFFF0000u);
    }
#pragma unroll
    for (int off = 8; off < 64; off <<= 1) {
        a0 += __shfl_xor(a0, off);
        a1 += __shfl_xor(a1, off);
        a2 += __shfl_xor(a2, off);
        a3 += __shfl_xor(a3, off);
        a4 += __shfl_xor(a4, off);
        a5 += __shfl_xor(a5, off);
        a6 += __shfl_xor(a6, off);
        a7 += __shfl_xor(a7, off);
    }
    if (g == 0) {
        size_t o = (size_t)node * 16 + q * 2;
        out4[o]     = make_float4(a0, a1, a2, a3);
        out4[o + 1] = make_float4(a4, a5, a6, a7);
    }
}

__global__ void atomic_scatter_kernel(const float* __restrict__ src_emb,
                                      const int* __restrict__ esrc,
                                      const int* __restrict__ edst,
                                      float* __restrict__ out, int n_edges) {
    int tid = blockIdx.x * blockDim.x + threadIdx.x;
    int e = tid >> 4;
    int q = tid & 15;
    if (e >= n_edges) return;
    int s = esrc[e];
    int d = edst[e];
    const float4* srow = reinterpret_cast<const float4*>(src_emb);
    float4 v = srow[(size_t)s * 16 + q];
    float* orow = out + (size_t)d * 64 + (size_t)q * 4;
    atomicAdd(orow + 0, v.x);
    atomicAdd(orow + 1, v.y);
    atomicAdd(orow + 2, v.z);
    atomicAdd(orow + 3, v.w);
}

extern "C" void kernel_launch(void* const* d_in, const int* in_sizes, int n_in,
                              void* d_out, int out_size, void* d_ws, size_t ws_size,
                              hipStream_t stream) {
    const float* src_emb = (const float*)d_in[0];
    const int* edge_src  = (const int*)d_in[1];
    const int* edge_dst  = (const int*)d_in[2];
    float* out = (float*)d_out;

    const int n_edges = in_sizes[1];
    const int n_src   = in_sizes[0] / 64;
    const int n_dst   = out_size / 64;

    const int B = 256;
    long n8 = (long)n_src * 8;
    size_t ws_ints = ws_size / sizeof(int);
    int nbins = (n_dst + DPB - 1) >> BIN_SHIFT;
    int nodes_per_block = B / 64;
    int agrid = (n_dst + nodes_per_block - 1) / nodes_per_block;

    // ---------- tier-0: fixed-stride bins, relative cursors ----------
    // ints: srcb[n_src*32] | cursor[nbins] spill_cnt[1] | offsets[n_dst] |
    //       ends[n_dst] | spill[2*spill_max] | packed[nbins*cap]
    if (n_dst > 0 && n_edges > 0 && n_src > 0 && n_src <= (1 << 20) &&
        nbins >= 1 && nbins <= 1024) {
        size_t srcb_ints = (size_t)n_src * 32;
        int spill_max = 65536;
        size_t fixed = srcb_ints + nbins + 1 + 2 * (size_t)n_dst +
                       2 * (size_t)spill_max;
        if (ws_ints > fixed) {
            long cap_l = (long)((ws_ints - fixed) / (size_t)nbins);
            int cap = cap_l > 8192 ? 8192 : (int)cap_l;
            long avg = (long)n_edges / nbins;
            if (cap >= 3072 && (long)cap >= avg + 512 &&
                (size_t)(cap + 2 * DPB) * 4 <= 64 * 1024) {
                uint4* srcb    = (uint4*)d_ws;
                int* cursor    = (int*)d_ws + srcb_ints;     // [nbins]
                int* spill_cnt = cursor + nbins;             // [1]
                int* offsets   = spill_cnt + 1;              // [n_dst]
                int* ends      = offsets + n_dst;            // [n_dst]
                int2* spill    = (int2*)(ends + n_dst);      // [spill_max]
                int* packed    = (int*)(spill + spill_max);  // [nbins*cap]

                int eblocks = (n_edges + EPB - 1) / EPB;

                hipMemsetAsync(cursor, 0, ((size_t)nbins + 1) * sizeof(int),
                               stream);
                scatter_convert_kernel<<<eblocks, 512, 0, stream>>>(
                    reinterpret_cast<const float4*>(src_emb), srcb, n8,
                    edge_src, edge_dst, cursor, packed, cap,
                    spill, spill_cnt, spill_max, nbins, n_edges);
                size_t shmem = (size_t)(cap + 2 * DPB) * sizeof(int);
                bin_sort_lds_kernel<<<nbins, 512, shmem, stream>>>(
                    packed, cursor, offsets, ends, cap, nbins, n_dst);
                accum_fix_bf16<<<agrid, B, 0, stream>>>(
                    srcb, offsets, ends, packed,
                    reinterpret_cast<float4*>(out), n_dst);
                spill_add_kernel<<<16, B, 0, stream>>>(
                    src_emb, spill, spill_cnt, spill_max, out);
                return;
            }
        }
    }

    // ---------- tier-1: proven R15 pipeline (81.4us) ----------
    {
        size_t srcb_ints = (size_t)n_src * 32;
        size_t need1 = srcb_ints + (size_t)nbins + 1 + nbins +
                       (size_t)n_edges + (size_t)n_dst + 1 + (size_t)n_edges;
        if (n_dst > 0 && n_edges > 0 && n_src > 0 && n_src <= (1 << 20) &&
            nbins >= 1 && nbins <= 1024 && ws_ints >= need1) {
            uint4* srcb     = (uint4*)d_ws;
            int* binOff     = (int*)d_ws + srcb_ints;
            int* cursor     = binOff + nbins + 1;
            int* packed     = cursor + nbins;
            int* offsets    = packed + n_edges;
            int* sorted_src = offsets + n_dst + 1;

            int eblocks = (n_edges + 4096 - 1) / 4096;

            convert_bf16_kernel<<<(int)((n8 + B - 1) / B), B, 0, stream>>>(
                reinterpret_cast<const float4*>(src_emb), srcb, n8);
            hipMemsetAsync(binOff, 0, ((size_t)nbins + 1) * sizeof(int), stream);
            bin_hist_kernel<<<eblocks, 512, 0, stream>>>(edge_dst, binOff,
                                                         nbins, n_edges);
            bin_scan_kernel<<<1, 1024, 0, stream>>>(binOff, cursor, nbins);
            bin_scatter_kernel<<<eblocks, 512, 0, stream>>>(edge_src, edge_dst,
                                                            cursor, packed,
                                                            nbins, n_edges);
            bin_sort_kernel<<<nbins, DPB, 0, stream>>>(packed, binOff,
                                                       sorted_src, offsets,
                                                       nbins, n_dst, n_edges);
            accum_abs_bf16<<<agrid, B, 0, stream>>>(
                srcb, offsets, sorted_src,
                reinterpret_cast<float4*>(out), n_dst);
            return;
        }
    }

    // ---------- tier-2: direct atomic fallback ----------
    hipMemsetAsync(d_out, 0, (size_t)out_size * sizeof(float), stream);
    int total = n_edges * 16;
    atomic_scatter_kernel<<<(total + 255) / 256, 256, 0, stream>>>(
        src_emb, edge_src, edge_dst, out, n_edges);
}

// Round 18
// 71.388 us; speedup vs baseline: 1.0172x; 1.0172x over previous
//
#include <hip/hip_runtime.h>

// HeteroConv copy_u + segment_sum.
// Ladder: 858 -> 71.5us (R16). Structure: fixed-stride bins (bin=dst>>8),
// fused {bin-scatter + bf16 convert} -> per-bin LDS counting sort (in-place)
// -> parallel bf16 accum -> exact spill.
// R17 bundled {relative cursors, EPB 8192, sort-512} and was NEUTRAL --
// EPB 8192 made the scatter write phase a 16-deep serial LDS-atomic chain,
// cancelling the other gains. R18 (this): UNTANGLE -- revert EPB to 4096
// (8 edges/thread, R16-proven), keep relative cursors + 512-thread sort.
// If flat again: pipeline is at its structural floor (accum at the random-
// gather ceiling; scatter at the LDS-chain rate; rest is dispatch gaps).

#define DPB 256          // dsts per bin
#define BIN_SHIFT 8
#define EPB 4096         // edges per scatter block (512 thr x 8)

__device__ __forceinline__ unsigned short f2bf(float f) {
    unsigned u = __float_as_uint(f);
    unsigned r = u + 0x7FFFu + ((u >> 16) & 1u);   // round-to-nearest-even
    return (unsigned short)(r >> 16);
}
__device__ __forceinline__ unsigned pack2(float lo, float hi) {
    return (unsigned)f2bf(lo) | ((unsigned)f2bf(hi) << 16);
}

// ---- tier-0 phase 1: fused bin-scatter + bf16 convert ----
// Relative cursors (start at 0): reservation base = atomicAdd(&cursor[k],c);
// global slot = k*cap + base + r. Overflow (base+r >= cap) -> spill list.
// Grid-strided bf16 convert runs between the reservation atomics and their
// use, hiding their latency.
__global__ void scatter_convert_kernel(const float4* __restrict__ src4,
                                       uint4* __restrict__ srcb, long n8,
                                       const int* __restrict__ esrc,
                                       const int* __restrict__ edst,
                                       int* __restrict__ cursor,
                                       int* __restrict__ packed, int cap,
                                       int2* __restrict__ spill,
                                       int* __restrict__ spill_cnt,
                                       int spill_max, int nbins, int n) {
    __shared__ int lc[1024];
    __shared__ int lbase[1024];
    __shared__ int lrank[1024];
    int t = threadIdx.x;
    for (int k = t; k < nbins; k += blockDim.x) { lc[k] = 0; lrank[k] = 0; }
    __syncthreads();

    int i0 = blockIdx.x * EPB + t * 8;
    bool fast = (i0 + 7 < n);

    if (fast) {
        int4 d0 = *reinterpret_cast<const int4*>(edst + i0);
        int4 d1 = *reinterpret_cast<const int4*>(edst + i0 + 4);
        atomicAdd(&lc[d0.x >> BIN_SHIFT], 1);
        atomicAdd(&lc[d0.y >> BIN_SHIFT], 1);
        atomicAdd(&lc[d0.z >> BIN_SHIFT], 1);
        atomicAdd(&lc[d0.w >> BIN_SHIFT], 1);
        atomicAdd(&lc[d1.x >> BIN_SHIFT], 1);
        atomicAdd(&lc[d1.y >> BIN_SHIFT], 1);
        atomicAdd(&lc[d1.z >> BIN_SHIFT], 1);
        atomicAdd(&lc[d1.w >> BIN_SHIFT], 1);
    } else {
        for (int k = 0; k < 8; ++k) {
            int i = i0 + k;
            if (i < n) atomicAdd(&lc[edst[i] >> BIN_SHIFT], 1);
        }
    }
    __syncthreads();

    // reserve ranges (return atomics; ~nbins per block)
    for (int k = t; k < nbins; k += blockDim.x) {
        int c = lc[k];
        if (c > 0) lbase[k] = atomicAdd(&cursor[k], c);
    }

    // fused bf16 convert: independent streaming work hides atomic latency
    long nthreads = (long)gridDim.x * blockDim.x;
    for (long u = (long)blockIdx.x * blockDim.x + t; u < n8; u += nthreads) {
        float4 a = src4[u * 2];
        float4 b = src4[u * 2 + 1];
        uint4 o;
        o.x = pack2(a.x, a.y);
        o.y = pack2(a.z, a.w);
        o.z = pack2(b.x, b.y);
        o.w = pack2(b.z, b.w);
        srcb[u] = o;
    }
    __syncthreads();

    if (fast) {
        int4 s0 = *reinterpret_cast<const int4*>(esrc + i0);
        int4 s1 = *reinterpret_cast<const int4*>(esrc + i0 + 4);
        int4 d0 = *reinterpret_cast<const int4*>(edst + i0);
        int4 d1 = *reinterpret_cast<const int4*>(edst + i0 + 4);
        int dd[8] = {d0.x, d0.y, d0.z, d0.w, d1.x, d1.y, d1.z, d1.w};
        int ss[8] = {s0.x, s0.y, s0.z, s0.w, s1.x, s1.y, s1.z, s1.w};
#pragma unroll
        for (int e = 0; e < 8; ++e) {
            int d = dd[e], s = ss[e];
            int k = d >> BIN_SHIFT;
            int r = lbase[k] + atomicAdd(&lrank[k], 1);
            if (r < cap) {
                packed[(size_t)k * cap + r] = ((d & (DPB - 1)) << 20) | s;
            } else {
                int sp = atomicAdd(spill_cnt, 1);
                if (sp < spill_max) spill[sp] = make_int2(s, d);
            }
        }
    } else {
        for (int kk = 0; kk < 8; ++kk) {
            int i = i0 + kk;
            if (i < n) {
                int d = edst[i], s = esrc[i];
                int k = d >> BIN_SHIFT;
                int r = lbase[k] + atomicAdd(&lrank[k], 1);
                if (r < cap) {
                    packed[(size_t)k * cap + r] = ((d & (DPB - 1)) << 20) | s;
                } else {
                    int sp = atomicAdd(spill_cnt, 1);
                    if (sp < spill_max) spill[sp] = make_int2(s, d);
                }
            }
        }
    }
}

// ---- tier-0 phase 2: per-bin LDS counting sort, in-place, 512 threads ----
__global__ void bin_sort_lds_kernel(int* __restrict__ packed,
                                    const int* __restrict__ cursor,
                                    int* __restrict__ offsets,
                                    int* __restrict__ ends,
                                    int cap, int nbins, int n_dst) {
    extern __shared__ int smem[];
    int* buf  = smem;          // [cap]
    int* cnt  = smem + cap;    // [256]
    int* base = cnt + DPB;     // [256]
    int t = threadIdx.x;       // 512 threads
    int b = blockIdx.x;
    int start = b * cap;
    int count = cursor[b];     // relative fill level
    if (count > cap) count = cap;
    if (count < 0) count = 0;

    for (int j = t; j < count; j += 512) buf[j] = packed[start + j];
    if (t < DPB) cnt[t] = 0;
    __syncthreads();

    for (int j = t; j < count; j += 512)
        atomicAdd(&cnt[(buf[j] >> 20) & (DPB - 1)], 1);
    __syncthreads();

    int v = 0;
    if (t < DPB) { v = cnt[t]; base[t] = v; }
    __syncthreads();
    for (int o = 1; o < DPB; o <<= 1) {
        int u = (t >= o && t < DPB) ? base[t - o] : 0;
        __syncthreads();
        if (t < DPB) base[t] += u;
        __syncthreads();
    }
    if (t < DPB) {
        int excl = base[t] - v;
        base[t] = excl;
        cnt[t] = 0;
        int g = (b << BIN_SHIFT) + t;
        if (g < n_dst) {
            offsets[g] = start + excl;
            ends[g]    = start + excl + v;
        }
    }
    __syncthreads();

    for (int j = t; j < count; j += 512) {
        int p = buf[j];
        int dl = (p >> 20) & (DPB - 1);
        int r = atomicAdd(&cnt[dl], 1);
        packed[start + base[dl] + r] = p & 0xFFFFF;   // src index only
    }
}

// ---- tier-0 phase 3: parallel bf16 accum (proven; traffic-floor) ----
__global__ void accum_fix_bf16(const uint4* __restrict__ srcb,
                               const int* __restrict__ offsets,
                               const int* __restrict__ ends,
                               const int* __restrict__ sorted_src,
                               float4* __restrict__ out4, int n_dst) {
    int node = blockIdx.x * (blockDim.x >> 6) + (threadIdx.x >> 6);
    if (node >= n_dst) return;
    int lane = threadIdx.x & 63;
    int g = lane >> 3;
    int q = lane & 7;

    int start = offsets[node];
    int end = ends[node];

    float a0 = 0.f, a1 = 0.f, a2 = 0.f, a3 = 0.f;
    float a4 = 0.f, a5 = 0.f, a6 = 0.f, a7 = 0.f;

    for (int j = start + g; j < end; j += 8) {
        int s = sorted_src[j];
        uint4 v = srcb[(size_t)s * 8 + q];
        a0 += __uint_as_float(v.x << 16);
        a1 += __uint_as_float(v.x & 0xFFFF0000u);
        a2 += __uint_as_float(v.y << 16);
        a3 += __uint_as_float(v.y & 0xFFFF0000u);
        a4 += __uint_as_float(v.z << 16);
        a5 += __uint_as_float(v.z & 0xFFFF0000u);
        a6 += __uint_as_float(v.w << 16);
        a7 += __uint_as_float(v.w & 0xFFFF0000u);
    }

#pragma unroll
    for (int off = 8; off < 64; off <<= 1) {    // uniform across the wave
        a0 += __shfl_xor(a0, off);
        a1 += __shfl_xor(a1, off);
        a2 += __shfl_xor(a2, off);
        a3 += __shfl_xor(a3, off);
        a4 += __shfl_xor(a4, off);
        a5 += __shfl_xor(a5, off);
        a6 += __shfl_xor(a6, off);
        a7 += __shfl_xor(a7, off);
    }
    if (g == 0) {
        size_t o = (size_t)node * 16 + q * 2;
        out4[o]     = make_float4(a0, a1, a2, a3);
        out4[o + 1] = make_float4(a4, a5, a6, a7);
    }
}

// ---- tier-0 phase 4: apply spill edges exactly (runs AFTER accum) ----
__global__ void spill_add_kernel(const float* __restrict__ src_emb,
                                 const int2* __restrict__ spill,
                                 const int* __restrict__ spill_cnt,
                                 int spill_max, float* __restrict__ out) {
    int n = *spill_cnt;
    if (n > spill_max) n = spill_max;
    long total = (long)n * 16;
    long stride = (long)gridDim.x * blockDim.x;
    for (long u = (long)blockIdx.x * blockDim.x + threadIdx.x; u < total;
         u += stride) {
        int e = (int)(u >> 4);
        int q = (int)(u & 15);
        int2 p = spill[e];
        const float* row = src_emb + (size_t)p.x * 64 + q * 4;
        float* orow = out + (size_t)p.y * 64 + q * 4;
        atomicAdd(orow + 0, row[0]);
        atomicAdd(orow + 1, row[1]);
        atomicAdd(orow + 2, row[2]);
        atomicAdd(orow + 3, row[3]);
    }
}

// ============ tier-1: proven R15 pipeline (81.4us) ============

__global__ void convert_bf16_kernel(const float4* __restrict__ src4,
                                    uint4* __restrict__ srcb, long n8) {
    long t = (long)blockIdx.x * blockDim.x + threadIdx.x;
    if (t >= n8) return;
    float4 a = src4[t * 2];
    float4 b = src4[t * 2 + 1];
    uint4 o;
    o.x = pack2(a.x, a.y);
    o.y = pack2(a.z, a.w);
    o.z = pack2(b.x, b.y);
    o.w = pack2(b.z, b.w);
    srcb[t] = o;
}

__global__ void bin_hist_kernel(const int* __restrict__ edst,
                                int* __restrict__ binCounts,
                                int nbins, int n) {
    __shared__ int lc[1024];
    int t = threadIdx.x;
    for (int k = t; k < nbins; k += blockDim.x) lc[k] = 0;
    __syncthreads();
    int i0 = blockIdx.x * 4096 + t * 8;
    if (i0 + 7 < n) {
        int4 d0 = *reinterpret_cast<const int4*>(edst + i0);
        int4 d1 = *reinterpret_cast<const int4*>(edst + i0 + 4);
        atomicAdd(&lc[d0.x >> BIN_SHIFT], 1);
        atomicAdd(&lc[d0.y >> BIN_SHIFT], 1);
        atomicAdd(&lc[d0.z >> BIN_SHIFT], 1);
        atomicAdd(&lc[d0.w >> BIN_SHIFT], 1);
        atomicAdd(&lc[d1.x >> BIN_SHIFT], 1);
        atomicAdd(&lc[d1.y >> BIN_SHIFT], 1);
        atomicAdd(&lc[d1.z >> BIN_SHIFT], 1);
        atomicAdd(&lc[d1.w >> BIN_SHIFT], 1);
    } else {
        for (int k = 0; k < 8; ++k) {
            int i = i0 + k;
            if (i < n) atomicAdd(&lc[edst[i] >> BIN_SHIFT], 1);
        }
    }
    __syncthreads();
    for (int k = t; k < nbins; k += blockDim.x) {
        int c = lc[k];
        if (c > 0) atomicAdd(&binCounts[k], c);
    }
}

__global__ void bin_scan_kernel(int* __restrict__ binOff,
                                int* __restrict__ cursor, int nbins) {
    __shared__ int lds[1024];
    int t = threadIdx.x;
    int v = (t < nbins) ? binOff[t] : 0;
    lds[t] = v;
    __syncthreads();
    for (int off = 1; off < 1024; off <<= 1) {
        int u = (t >= off) ? lds[t - off] : 0;
        __syncthreads();
        lds[t] += u;
        __syncthreads();
    }
    if (t < nbins) {
        int base = lds[t] - v;
        binOff[t] = base;
        cursor[t] = base;
    }
    if (t == 1023) binOff[nbins] = lds[t];
}

__global__ void bin_scatter_kernel(const int* __restrict__ esrc,
                                   const int* __restrict__ edst,
                                   int* __restrict__ cursor,
                                   int* __restrict__ packed,
                                   int nbins, int n) {
    __shared__ int lc[1024];
    __shared__ int lbase[1024];
    __shared__ int lrank[1024];
    int t = threadIdx.x;
    for (int k = t; k < nbins; k += blockDim.x) { lc[k] = 0; lrank[k] = 0; }
    __syncthreads();
    int i0 = blockIdx.x * 4096 + t * 8;
    bool fast = (i0 + 7 < n);
    if (fast) {
        int4 d0 = *reinterpret_cast<const int4*>(edst + i0);
        int4 d1 = *reinterpret_cast<const int4*>(edst + i0 + 4);
        atomicAdd(&lc[d0.x >> BIN_SHIFT], 1);
        atomicAdd(&lc[d0.y >> BIN_SHIFT], 1);
        atomicAdd(&lc[d0.z >> BIN_SHIFT], 1);
        atomicAdd(&lc[d0.w >> BIN_SHIFT], 1);
        atomicAdd(&lc[d1.x >> BIN_SHIFT], 1);
        atomicAdd(&lc[d1.y >> BIN_SHIFT], 1);
        atomicAdd(&lc[d1.z >> BIN_SHIFT], 1);
        atomicAdd(&lc[d1.w >> BIN_SHIFT], 1);
    } else {
        for (int k = 0; k < 8; ++k) {
            int i = i0 + k;
            if (i < n) atomicAdd(&lc[edst[i] >> BIN_SHIFT], 1);
        }
    }
    __syncthreads();
    for (int k = t; k < nbins; k += blockDim.x) {
        int c = lc[k];
        if (c > 0) lbase[k] = atomicAdd(&cursor[k], c);
    }
    __syncthreads();
    if (fast) {
        int4 s0 = *reinterpret_cast<const int4*>(esrc + i0);
        int4 s1 = *reinterpret_cast<const int4*>(esrc + i0 + 4);
        int4 d0 = *reinterpret_cast<const int4*>(edst + i0);
        int4 d1 = *reinterpret_cast<const int4*>(edst + i0 + 4);
        int dd[8] = {d0.x, d0.y, d0.z, d0.w, d1.x, d1.y, d1.z, d1.w};
        int ss[8] = {s0.x, s0.y, s0.z, s0.w, s1.x, s1.y, s1.z, s1.w};
#pragma unroll
        for (int e = 0; e < 8; ++e) {
            int k = dd[e] >> BIN_SHIFT;
            int r = atomicAdd(&lrank[k], 1);
            packed[lbase[k] + r] = ((dd[e] & (DPB - 1)) << 20) | ss[e];
        }
    } else {
        for (int kk = 0; kk < 8; ++kk) {
            int i = i0 + kk;
            if (i < n) {
                int d = edst[i];
                int k = d >> BIN_SHIFT;
                int r = atomicAdd(&lrank[k], 1);
                packed[lbase[k] + r] = ((d & (DPB - 1)) << 20) | esrc[i];
            }
        }
    }
}

__global__ void bin_sort_kernel(const int* __restrict__ packed,
                                const int* __restrict__ binOff,
                                int* __restrict__ sorted_src,
                                int* __restrict__ offsets,
                                int nbins, int n_dst, int n_edges) {
    __shared__ int cnt[DPB];
    __shared__ int base[DPB];
    int t = threadIdx.x;
    int b = blockIdx.x;
    int start = binOff[b];
    int end = binOff[b + 1];
    cnt[t] = 0;
    __syncthreads();
    for (int j = start + t; j < end; j += DPB)
        atomicAdd(&cnt[(packed[j] >> 20) & (DPB - 1)], 1);
    __syncthreads();
    int v = cnt[t];
    base[t] = v;
    __syncthreads();
    for (int o = 1; o < DPB; o <<= 1) {
        int u = (t >= o) ? base[t - o] : 0;
        __syncthreads();
        base[t] += u;
        __syncthreads();
    }
    int my_excl = base[t] - v;
    __syncthreads();
    base[t] = my_excl;
    cnt[t] = 0;
    int g = (b << BIN_SHIFT) + t;
    if (g < n_dst) offsets[g] = start + my_excl;
    if (b == nbins - 1 && t == 0) offsets[n_dst] = n_edges;
    __syncthreads();
    for (int j = start + t; j < end; j += DPB) {
        int p = packed[j];
        int dl = (p >> 20) & (DPB - 1);
        int r = atomicAdd(&cnt[dl], 1);
        sorted_src[start + base[dl] + r] = p & 0xFFFFF;
    }
}

__global__ void accum_abs_bf16(const uint4* __restrict__ srcb,
                               const int* __restrict__ offsets,
                               const int* __restrict__ sorted_src,
                               float4* __restrict__ out4, int n_dst) {
    int node = blockIdx.x * (blockDim.x >> 6) + (threadIdx.x >> 6);
    if (node >= n_dst) return;
    int lane = threadIdx.x & 63;
    int g = lane >> 3;
    int q = lane & 7;
    int start = offsets[node];
    int end = offsets[node + 1];
    float a0 = 0.f, a1 = 0.f, a2 = 0.f, a3 = 0.f;
    float a4 = 0.f, a5 = 0.f, a6 = 0.f, a7 = 0.f;
    for (int j = start + g; j < end; j += 8) {
        int s = sorted_src[j];
        uint4 v = srcb[(size_t)s * 8 + q];
        a0 += __uint_as_float(v.x << 16);
        a1 += __uint_as_float(v.x & 0xFFFF0000u);
        a2 += __uint_as_float(v.y << 16);
        a3 += __uint_as_float(v.y & 0xFFFF0000u);
        a4 += __uint_as_float(v.z << 16);
        a5 += __uint_as_float(v.z & 0xFFFF0000u);
        a6 += __uint_as_float(v.w << 16);
        a7 += __uint_as_float(v.w & 0xFFFF0000u);
    }
#pragma unroll
    for (int off = 8; off < 64; off <<= 1) {
        a0 += __shfl_xor(a0, off);
        a1 += __shfl_xor(a1, off);
        a2 += __shfl_xor(a2, off);
        a3 += __shfl_xor(a3, off);
        a4 += __shfl_xor(a4, off);
        a5 += __shfl_xor(a5, off);
        a6 += __shfl_xor(a6, off);
        a7 += __shfl_xor(a7, off);
    }
    if (g == 0) {
        size_t o = (size_t)node * 16 + q * 2;
        out4[o]     = make_float4(a0, a1, a2, a3);
        out4[o + 1] = make_float4(a4, a5, a6, a7);
    }
}

__global__ void atomic_scatter_kernel(const float* __restrict__ src_emb,
                                      const int* __restrict__ esrc,
                                      const int* __restrict__ edst,
                                      float* __restrict__ out, int n_edges) {
    int tid = blockIdx.x * blockDim.x + threadIdx.x;
    int e = tid >> 4;
    int q = tid & 15;
    if (e >= n_edges) return;
    int s = esrc[e];
    int d = edst[e];
    const float4* srow = reinterpret_cast<const float4*>(src_emb);
    float4 v = srow[(size_t)s * 16 + q];
    float* orow = out + (size_t)d * 64 + (size_t)q * 4;
    atomicAdd(orow + 0, v.x);
    atomicAdd(orow + 1, v.y);
    atomicAdd(orow + 2, v.z);
    atomicAdd(orow + 3, v.w);
}

extern "C" void kernel_launch(void* const* d_in, const int* in_sizes, int n_in,
                              void* d_out, int out_size, void* d_ws, size_t ws_size,
                              hipStream_t stream) {
    const float* src_emb = (const float*)d_in[0];
    const int* edge_src  = (const int*)d_in[1];
    const int* edge_dst  = (const int*)d_in[2];
    float* out = (float*)d_out;

    const int n_edges = in_sizes[1];
    const int n_src   = in_sizes[0] / 64;
    const int n_dst   = out_size / 64;

    const int B = 256;
    long n8 = (long)n_src * 8;
    size_t ws_ints = ws_size / sizeof(int);
    int nbins = (n_dst + DPB - 1) >> BIN_SHIFT;
    int nodes_per_block = B / 64;
    int agrid = (n_dst + nodes_per_block - 1) / nodes_per_block;

    // ---------- tier-0: fixed-stride bins, relative cursors ----------
    // ints: srcb[n_src*32] | cursor[nbins] spill_cnt[1] | offsets[n_dst] |
    //       ends[n_dst] | spill[2*spill_max] | packed[nbins*cap]
    if (n_dst > 0 && n_edges > 0 && n_src > 0 && n_src <= (1 << 20) &&
        nbins >= 1 && nbins <= 1024) {
        size_t srcb_ints = (size_t)n_src * 32;
        int spill_max = 65536;
        size_t fixed = srcb_ints + nbins + 1 + 2 * (size_t)n_dst +
                       2 * (size_t)spill_max;
        if (ws_ints > fixed) {
            long cap_l = (long)((ws_ints - fixed) / (size_t)nbins);
            int cap = cap_l > 8192 ? 8192 : (int)cap_l;
            long avg = (long)n_edges / nbins;
            if (cap >= 3072 && (long)cap >= avg + 512 &&
                (size_t)(cap + 2 * DPB) * 4 <= 64 * 1024) {
                uint4* srcb    = (uint4*)d_ws;
                int* cursor    = (int*)d_ws + srcb_ints;     // [nbins]
                int* spill_cnt = cursor + nbins;             // [1]
                int* offsets   = spill_cnt + 1;              // [n_dst]
                int* ends      = offsets + n_dst;            // [n_dst]
                int2* spill    = (int2*)(ends + n_dst);      // [spill_max]
                int* packed    = (int*)(spill + spill_max);  // [nbins*cap]

                int eblocks = (n_edges + EPB - 1) / EPB;

                hipMemsetAsync(cursor, 0, ((size_t)nbins + 1) * sizeof(int),
                               stream);
                scatter_convert_kernel<<<eblocks, 512, 0, stream>>>(
                    reinterpret_cast<const float4*>(src_emb), srcb, n8,
                    edge_src, edge_dst, cursor, packed, cap,
                    spill, spill_cnt, spill_max, nbins, n_edges);
                size_t shmem = (size_t)(cap + 2 * DPB) * sizeof(int);
                bin_sort_lds_kernel<<<nbins, 512, shmem, stream>>>(
                    packed, cursor, offsets, ends, cap, nbins, n_dst);
                accum_fix_bf16<<<agrid, B, 0, stream>>>(
                    srcb, offsets, ends, packed,
                    reinterpret_cast<float4*>(out), n_dst);
                spill_add_kernel<<<16, B, 0, stream>>>(
                    src_emb, spill, spill_cnt, spill_max, out);
                return;
            }
        }
    }

    // ---------- tier-1: proven R15 pipeline (81.4us) ----------
    {
        size_t srcb_ints = (size_t)n_src * 32;
        size_t need1 = srcb_ints + (size_t)nbins + 1 + nbins +
                       (size_t)n_edges + (size_t)n_dst + 1 + (size_t)n_edges;
        if (n_dst > 0 && n_edges > 0 && n_src > 0 && n_src <= (1 << 20) &&
            nbins >= 1 && nbins <= 1024 && ws_ints >= need1) {
            uint4* srcb     = (uint4*)d_ws;
            int* binOff     = (int*)d_ws + srcb_ints;
            int* cursor     = binOff + nbins + 1;
            int* packed     = cursor + nbins;
            int* offsets    = packed + n_edges;
            int* sorted_src = offsets + n_dst + 1;

            int eblocks = (n_edges + 4096 - 1) / 4096;

            convert_bf16_kernel<<<(int)((n8 + B - 1) / B), B, 0, stream>>>(
                reinterpret_cast<const float4*>(src_emb), srcb, n8);
            hipMemsetAsync(binOff, 0, ((size_t)nbins + 1) * sizeof(int), stream);
            bin_hist_kernel<<<eblocks, 512, 0, stream>>>(edge_dst, binOff,
                                                         nbins, n_edges);
            bin_scan_kernel<<<1, 1024, 0, stream>>>(binOff, cursor, nbins);
            bin_scatter_kernel<<<eblocks, 512, 0, stream>>>(edge_src, edge_dst,
                                                            cursor, packed,
                                                            nbins, n_edges);
            bin_sort_kernel<<<nbins, DPB, 0, stream>>>(packed, binOff,
                                                       sorted_src, offsets,
                                                       nbins, n_dst, n_edges);
            accum_abs_bf16<<<agrid, B, 0, stream>>>(
                srcb, offsets, sorted_src,
                reinterpret_cast<float4*>(out), n_dst);
            return;
        }
    }

    // ---------- tier-2: direct atomic fallback ----------
    hipMemsetAsync(d_out, 0, (size_t)out_size * sizeof(float), stream);
    int total = n_edges * 16;
    atomic_scatter_kernel<<<(total + 255) / 256, 256, 0, stream>>>(
        src_emb, edge_src, edge_dst, out, n_edges);
}